// Round 4
// baseline (218.679 us; speedup 1.0000x reference)
//
#include <hip/hip_runtime.h>

typedef _Float16 h4 __attribute__((ext_vector_type(4)));
typedef _Float16 h8 __attribute__((ext_vector_type(8)));
typedef float    f4 __attribute__((ext_vector_type(4)));

// SCALE * log2(e): softmax computed in exp2 domain (identical result).
// No max-subtraction: |s_scaled| < ~6 here -> exp2 in [2e-2, 45], fp16/fp32 safe.
#define QSCALE (0.25f * 1.44269504088896f)

__device__ __forceinline__ float ex2(float x){ return __builtin_amdgcn_exp2f(x); }

// ---------------- prep: fold BN into weights (weights only) ----------------
__global__ __launch_bounds__(256) void prep_k(
    const float* __restrict__ qkvw, const float* __restrict__ qg, const float* __restrict__ qb,
    const float* __restrict__ qm,   const float* __restrict__ qv,
    const float* __restrict__ pew,  const float* __restrict__ pg, const float* __restrict__ pb,
    const float* __restrict__ pm,   const float* __restrict__ pv,
    const float* __restrict__ prw,  const float* __restrict__ prg, const float* __restrict__ prb,
    const float* __restrict__ prm,  const float* __restrict__ prv,
    _Float16* __restrict__ Wqkv, float* __restrict__ bqkv,
    _Float16* __restrict__ Wproj, float* __restrict__ bproj,
    float* __restrict__ peW, float* __restrict__ peB)
{
  const int gid = blockIdx.x*256 + threadIdx.x;
  const int gsz = gridDim.x*256;
  for (int i = gid; i < 512*256; i += gsz){           // Wqkv[o][c] = w[c][o]*g*rs
    int o = i >> 8, c = i & 255;
    float s = qg[o] * rsqrtf(qv[o] + 1e-3f);
    Wqkv[i] = (_Float16)(qkvw[c*512 + o] * s);
  }
  for (int i = gid; i < 512; i += gsz){
    float s = qg[i] * rsqrtf(qv[i] + 1e-3f);
    bqkv[i] = qb[i] - qm[i]*s;
  }
  for (int i = gid; i < 256*256; i += gsz){
    int o = i >> 8, c = i & 255;
    float s = prg[o] * rsqrtf(prv[o] + 1e-3f);
    Wproj[i] = (_Float16)(prw[c*256 + o] * s);
  }
  for (int i = gid; i < 256; i += gsz){
    float s = prg[i] * rsqrtf(prv[i] + 1e-3f);
    bproj[i] = prb[i] - prm[i]*s;
  }
  for (int i = gid; i < 9*256; i += gsz){
    int c = i & 255;
    float s = pg[c] * rsqrtf(pv[c] + 1e-3f);
    peW[i] = pew[i] * s;
  }
  for (int i = gid; i < 256; i += gsz){
    float s = pg[i] * rsqrtf(pv[i] + 1e-3f);
    peB[i] = pb[i] - pm[i]*s;
  }
}

// ---------------- qkv GEMM: [8192 x 256(f32)] x [512 x 256]^T --------------
// LDS/barrier-free; A read fp32 from global, cvt in-register. Wave = 16m x 64n.
// grid (128, 8) = 1024 blocks -> 4 waves/SIMD.
__global__ __launch_bounds__(256) void qkv_gemm_k(
    const float* __restrict__ X, const _Float16* __restrict__ Wqkv,
    const float* __restrict__ bias,
    _Float16* __restrict__ Qh, _Float16* __restrict__ Kh, _Float16* __restrict__ Vh)
{
  const int t = threadIdx.x, lane = t & 63, wv = t >> 6;
  const int l15 = lane & 15, q = lane >> 4;
  const int mb = (blockIdx.x*4 + wv) * 16;
  const int n0 = blockIdx.y * 64;
  f4 acc[4] = {};
  #pragma unroll
  for (int kk = 0; kk < 8; ++kk){
    const float4 a0 = *(const float4*)(X + (size_t)(mb + l15)*256 + kk*32 + q*8);
    const float4 a1 = *(const float4*)(X + (size_t)(mb + l15)*256 + kk*32 + q*8 + 4);
    h8 af; af[0]=(_Float16)a0.x; af[1]=(_Float16)a0.y; af[2]=(_Float16)a0.z; af[3]=(_Float16)a0.w;
           af[4]=(_Float16)a1.x; af[5]=(_Float16)a1.y; af[6]=(_Float16)a1.z; af[7]=(_Float16)a1.w;
    #pragma unroll
    for (int nj = 0; nj < 4; ++nj){
      h8 bf = *(const h8*)(Wqkv + (size_t)(n0 + nj*16 + l15)*256 + kk*32 + q*8);
      acc[nj] = __builtin_amdgcn_mfma_f32_16x16x32_f16(af, bf, acc[nj], 0,0,0);
    }
  }
  #pragma unroll
  for (int nj = 0; nj < 4; ++nj){
    const int og = n0 + nj*16 + l15;
    const int j  = og & 63;          // wave-uniform range per nj
    const int h  = og >> 6;
    const float bs = bias[og];
    #pragma unroll
    for (int r = 0; r < 4; ++r){
      const int mg = mb + q*4 + r;
      const int b = mg >> 10, n = mg & 1023;
      const size_t bhn = (size_t)(b*8+h)*1024 + n;
      const float v = acc[nj][r] + bs;
      if (j < 16)      Qh[bhn*16 + j]      = (_Float16)(v * QSCALE);
      else if (j < 32) Kh[bhn*16 + (j-16)] = (_Float16)v;
      else             Vh[bhn*32 + (j-32)] = (_Float16)v;
    }
  }
}

// ---------------- pass1: rowsum of exp2 over m; Vs[d][n]=V[n][d]/sum -------
// Wave owns 16 n-rows; grid (16, 64) = 1024 blocks -> 4 waves/SIMD.
__global__ __launch_bounds__(256) void pass1_k(
    const _Float16* __restrict__ Qh, const _Float16* __restrict__ Kh,
    const _Float16* __restrict__ Vh, _Float16* __restrict__ Vs)
{
  const int t = threadIdx.x, lane = t & 63, wv = t >> 6;
  const int l15 = lane & 15, q = lane >> 4;
  const int bh = blockIdx.y;
  const int n0 = (blockIdx.x*4 + wv) * 16;
  const size_t qb = (size_t)bh*1024;
  const h4 af = *(const h4*)(Qh + (qb + n0 + l15)*16 + q*4);
  f4 sm = {0.f,0.f,0.f,0.f};
  const _Float16* kp = Kh + qb*16;
  #pragma unroll 8
  for (int mt = 0; mt < 64; ++mt){
    h4 bf = *(const h4*)(kp + mt*256 + l15*16 + q*4);
    f4 z = {0.f,0.f,0.f,0.f};
    f4 d = __builtin_amdgcn_mfma_f32_16x16x16f16(af, bf, z, 0,0,0);
    #pragma unroll
    for (int r = 0; r < 4; ++r) sm[r] += ex2(d[r]);
  }
  #pragma unroll
  for (int st = 1; st < 16; st <<= 1){
    #pragma unroll
    for (int r = 0; r < 4; ++r) sm[r] += __shfl_xor(sm[r], st, 64);
  }
  f4 cv;
  #pragma unroll
  for (int r = 0; r < 4; ++r) cv[r] = 1.0f/sm[r];
  // Vs[bh][d][n] = V[n][d] * invsum[n]  (fp16)
  #pragma unroll
  for (int half = 0; half < 2; ++half){
    const int dd = l15 + half*16;
    h4 o;
    #pragma unroll
    for (int r = 0; r < 4; ++r)
      o[r] = (_Float16)((float)Vh[(qb + n0 + q*4 + r)*32 + dd] * cv[r]);
    *(h4*)(Vs + ((size_t)bh*32 + dd)*1024 + n0 + q*4) = o;
  }
}

// ---------------- pass2: out[m][d] = sum_n exp2(s[n][m]) * Vs[d][n] --------
// Wave owns 16 m; grid (16, 64) = 1024 blocks -> 4 waves/SIMD. Barrier-free
// main loop (S-tile C/D layout IS the P^T A-frag layout); epilogue transposes
// the 16x32 (m,d) tile through LDS and stores X1h flat (b,d,h,m), which makes
// the reference transpose+reshape an identity on flat indices.
__global__ __launch_bounds__(256) void pass2_k(
    const _Float16* __restrict__ Qh, const _Float16* __restrict__ Kh,
    const _Float16* __restrict__ Vs, _Float16* __restrict__ X1h)
{
  __shared__ float Tt[4][16*33];
  const int t = threadIdx.x, lane = t & 63, wv = t >> 6;
  const int l15 = lane & 15, q = lane >> 4;
  const int bh = blockIdx.y;
  const int b  = bh >> 3, h = bh & 7;
  const int mb = (blockIdx.x*4 + wv) * 16;
  const size_t qb = (size_t)bh*1024;
  const h4 kf = *(const h4*)(Kh + (qb + mb + l15)*16 + q*4);   // loop-invariant
  const _Float16* qp  = Qh + qb*16;
  const _Float16* vp0 = Vs + ((size_t)bh*32 + l15)*1024;
  const _Float16* vp1 = vp0 + 16*1024;
  f4 a0 = {0.f,0.f,0.f,0.f}, a1 = {0.f,0.f,0.f,0.f};
  #pragma unroll 4
  for (int nt = 0; nt < 1024; nt += 16){
    h4 qf = *(const h4*)(qp + (nt + l15)*16 + q*4);
    h4 b0 = *(const h4*)(vp0 + nt + q*4);
    h4 b1 = *(const h4*)(vp1 + nt + q*4);
    f4 z = {0.f,0.f,0.f,0.f};
    f4 s = __builtin_amdgcn_mfma_f32_16x16x16f16(qf, kf, z, 0,0,0);
    h4 p;
    #pragma unroll
    for (int r = 0; r < 4; ++r) p[r] = (_Float16)ex2(s[r]);
    a0 = __builtin_amdgcn_mfma_f32_16x16x16f16(p, b0, a0, 0,0,0);
    a1 = __builtin_amdgcn_mfma_f32_16x16x16f16(p, b1, a1, 0,0,0);
  }
  // a0[r] = out[m=mb+4q+r][d=l15], a1 -> d=16+l15; transpose via LDS.
  #pragma unroll
  for (int r = 0; r < 4; ++r){
    Tt[wv][(q*4 + r)*33 + l15]      = a0[r];
    Tt[wv][(q*4 + r)*33 + 16 + l15] = a1[r];
  }
  __syncthreads();
  _Float16* xb = X1h + (size_t)b*262144 + (size_t)h*1024 + mb;
  #pragma unroll
  for (int r = 0; r < 8; ++r){
    const int d = r*4 + q;
    xb[(size_t)d*8192 + l15] = (_Float16)Tt[wv][l15*33 + d];
  }
}

// ---------------- pe depthwise 3x3 + add + cast to fp16 for proj ----------
__global__ __launch_bounds__(256) void pe_add_k(
    const _Float16* __restrict__ Vh, const _Float16* __restrict__ X1h,
    const float* __restrict__ peW, const float* __restrict__ peB,
    _Float16* __restrict__ X2h)
{
  const int idx = blockIdx.x*256 + threadIdx.x;   // (b,hs,ws,c) flat
  const int c = idx & 255;
  const int tok = idx >> 8;
  const int b = tok >> 10, n = tok & 1023;
  const int hs = n >> 5, ws = n & 31;
  const int h = c >> 5, d = c & 31;
  float acc = peB[c];
  const _Float16* vb = Vh + (size_t)(b*8 + h)*32768 + d;
  #pragma unroll
  for (int dy = 0; dy < 3; ++dy){
    const int y = hs + dy - 1;
    if ((unsigned)y < 32u){
      #pragma unroll
      for (int dx = 0; dx < 3; ++dx){
        const int x = ws + dx - 1;
        if ((unsigned)x < 32u)
          acc += peW[(dy*3+dx)*256 + c] * (float)vb[(size_t)(y*32 + x)*32];
      }
    }
  }
  X2h[idx] = (_Float16)((float)X1h[idx] + acc);
}

// ---------------- proj GEMM: [8192 x 256] x [256 x 256]^T ------------------
// Wave = 16m x 32n; grid (128, 8) = 1024 blocks -> 4 waves/SIMD.
__global__ __launch_bounds__(256) void proj_gemm_k(
    const _Float16* __restrict__ A, const _Float16* __restrict__ Wproj,
    const float* __restrict__ bias, float* __restrict__ Out)
{
  const int t = threadIdx.x, lane = t & 63, wv = t >> 6;
  const int l15 = lane & 15, q = lane >> 4;
  const int mb = (blockIdx.x*4 + wv) * 16;
  const int n0 = blockIdx.y * 32;
  f4 acc[2] = {};
  #pragma unroll
  for (int kk = 0; kk < 8; ++kk){
    h8 af = *(const h8*)(A + (size_t)(mb + l15)*256 + kk*32 + q*8);
    #pragma unroll
    for (int nj = 0; nj < 2; ++nj){
      h8 bf = *(const h8*)(Wproj + (size_t)(n0 + nj*16 + l15)*256 + kk*32 + q*8);
      acc[nj] = __builtin_amdgcn_mfma_f32_16x16x32_f16(af, bf, acc[nj], 0,0,0);
    }
  }
  #pragma unroll
  for (int nj = 0; nj < 2; ++nj){
    const int og = n0 + nj*16 + l15;
    const float bs = bias[og];
    #pragma unroll
    for (int r = 0; r < 4; ++r){
      const int mg = mb + q*4 + r;
      Out[(size_t)mg*256 + og] = acc[nj][r] + bs;
    }
  }
}

// --------------------------------------------------------------------------
extern "C" void kernel_launch(void* const* d_in, const int* in_sizes, int n_in,
                              void* d_out, int out_size, void* d_ws, size_t ws_size,
                              hipStream_t stream)
{
  const float* X    = (const float*)d_in[0];
  const float* qkvw = (const float*)d_in[1];
  const float* qg   = (const float*)d_in[2];
  const float* qb   = (const float*)d_in[3];
  const float* qm   = (const float*)d_in[4];
  const float* qv   = (const float*)d_in[5];
  const float* pew  = (const float*)d_in[6];
  const float* pg   = (const float*)d_in[7];
  const float* pb   = (const float*)d_in[8];
  const float* pm   = (const float*)d_in[9];
  const float* pv   = (const float*)d_in[10];
  const float* prw  = (const float*)d_in[11];
  const float* prg  = (const float*)d_in[12];
  const float* prb  = (const float*)d_in[13];
  const float* prm  = (const float*)d_in[14];
  const float* prv  = (const float*)d_in[15];

  char* ws = (char*)d_ws;
  _Float16* X2h   = (_Float16*)(ws + 0);          //  4 MB
  _Float16* Qh    = (_Float16*)(ws + 4194304);    //  2 MB (pre-scaled)
  _Float16* Kh    = (_Float16*)(ws + 6291456);    //  2 MB
  _Float16* Vh    = (_Float16*)(ws + 8388608);    //  4 MB  (bh,n,d)
  _Float16* Vs    = (_Float16*)(ws + 12582912);   //  4 MB  (bh,d,n), /rowsum
  _Float16* X1h   = (_Float16*)(ws + 16777216);   //  4 MB  (b,d,h,m)
  _Float16* Wqkv  = (_Float16*)(ws + 20971520);   //  256 KB [o][c]
  float*    bqkv  = (float*)   (ws + 21233664);   //  2 KB
  _Float16* Wproj = (_Float16*)(ws + 21235712);   //  128 KB [o][c]
  float*    bproj = (float*)   (ws + 21366784);   //  1 KB
  float*    peW   = (float*)   (ws + 21367808);   //  9 KB
  float*    peB   = (float*)   (ws + 21377024);   //  1 KB

  prep_k<<<128, 256, 0, stream>>>(qkvw, qg, qb, qm, qv, pew, pg, pb, pm, pv,
                                  prw, prg, prb, prm, prv,
                                  Wqkv, bqkv, Wproj, bproj, peW, peB);
  qkv_gemm_k<<<dim3(128, 8), 256, 0, stream>>>(X, Wqkv, bqkv, Qh, Kh, Vh);
  pass1_k<<<dim3(16, 64), 256, 0, stream>>>(Qh, Kh, Vh, Vs);
  pass2_k<<<dim3(16, 64), 256, 0, stream>>>(Qh, Kh, Vs, X1h);
  pe_add_k<<<8192, 256, 0, stream>>>(Vh, X1h, peW, peB, X2h);
  proj_gemm_k<<<dim3(128, 8), 256, 0, stream>>>(X2h, Wproj, bproj, (float*)d_out);
}

// Round 5
// 150.771 us; speedup vs baseline: 1.4504x; 1.4504x over previous
//
#include <hip/hip_runtime.h>

typedef _Float16 h4 __attribute__((ext_vector_type(4)));
typedef _Float16 h8 __attribute__((ext_vector_type(8)));
typedef float    f4 __attribute__((ext_vector_type(4)));

// SCALE * log2(e): softmax computed in exp2 domain (identical result).
// No max-subtraction: |s_scaled| < ~6 here -> exp2 in [2e-2, 45], fp16/fp32 safe.
#define QSCALE (0.25f * 1.44269504088896f)

__device__ __forceinline__ float ex2(float x){ return __builtin_amdgcn_exp2f(x); }

// ---------------- prep: fold BN into weights, X -> fp16 --------------------
__global__ __launch_bounds__(256) void prep_k(
    const float* __restrict__ X,
    const float* __restrict__ qkvw, const float* __restrict__ qg, const float* __restrict__ qb,
    const float* __restrict__ qm,   const float* __restrict__ qv,
    const float* __restrict__ pew,  const float* __restrict__ pg, const float* __restrict__ pb,
    const float* __restrict__ pm,   const float* __restrict__ pv,
    const float* __restrict__ prw,  const float* __restrict__ prg, const float* __restrict__ prb,
    const float* __restrict__ prm,  const float* __restrict__ prv,
    _Float16* __restrict__ Xh, _Float16* __restrict__ Wqkv, float* __restrict__ bqkv,
    _Float16* __restrict__ Wproj, float* __restrict__ bproj,
    float* __restrict__ peW, float* __restrict__ peB)
{
  const int gid = blockIdx.x*256 + threadIdx.x;
  const int gsz = gridDim.x*256;
  for (int i = gid; i < 2097152/4; i += gsz){
    const float4 xv = ((const float4*)X)[i];
    h4 o; o[0]=(_Float16)xv.x; o[1]=(_Float16)xv.y; o[2]=(_Float16)xv.z; o[3]=(_Float16)xv.w;
    ((h4*)Xh)[i] = o;
  }
  for (int i = gid; i < 512*256; i += gsz){           // Wqkv[o][c] = w[c][o]*g*rs
    int o = i >> 8, c = i & 255;
    float s = qg[o] * rsqrtf(qv[o] + 1e-3f);
    Wqkv[i] = (_Float16)(qkvw[c*512 + o] * s);
  }
  for (int i = gid; i < 512; i += gsz){
    float s = qg[i] * rsqrtf(qv[i] + 1e-3f);
    bqkv[i] = qb[i] - qm[i]*s;
  }
  for (int i = gid; i < 256*256; i += gsz){
    int o = i >> 8, c = i & 255;
    float s = prg[o] * rsqrtf(prv[o] + 1e-3f);
    Wproj[i] = (_Float16)(prw[c*256 + o] * s);
  }
  for (int i = gid; i < 256; i += gsz){
    float s = prg[i] * rsqrtf(prv[i] + 1e-3f);
    bproj[i] = prb[i] - prm[i]*s;
  }
  for (int i = gid; i < 9*256; i += gsz){
    int c = i & 255;
    float s = pg[c] * rsqrtf(pv[c] + 1e-3f);
    peW[i] = pew[i] * s;
  }
  for (int i = gid; i < 256; i += gsz){
    float s = pg[i] * rsqrtf(pv[i] + 1e-3f);
    peB[i] = pb[i] - pm[i]*s;
  }
}

// ---------------- staged GEMM: [M x 256] x [N x 256]^T, 16x16x32 f16 -------
// Block tile: BM x 64 (BM = MT*32), waves 2x2: wave = (MT*16 m) x (32 n).
// Single LDS buffer, 2 barriers/chunk, register prefetch of next K-chunk.
// EPI 0: qkv epilogue (split/scale Q,K,V); EPI 1: proj epilogue (fp32 out).
template<int EPI, int MT>
__global__ __launch_bounds__(256) void gemm_staged_k(
    const _Float16* __restrict__ A, const _Float16* __restrict__ Bt,
    const float* __restrict__ bias,
    _Float16* __restrict__ Qh, _Float16* __restrict__ Kh, _Float16* __restrict__ Vh,
    float* __restrict__ Out)
{
  constexpr int BM = MT*32;
  constexpr int AR = BM/64;                  // uint4 staged per thread for A
  __shared__ __align__(16) _Float16 As[BM*40];   // row stride 40 halves (80 B)
  __shared__ __align__(16) _Float16 Bs[64*40];
  const int t = threadIdx.x, lane = t & 63, wv = t >> 6;
  const int l15 = lane & 15, q = lane >> 4;
  const int wr = wv & 1, wc = wv >> 1;
  const int m0 = blockIdx.x*BM, n0 = blockIdx.y*64;
  const int r4 = t >> 2, s4 = t & 3;
  uint4 ar[AR], br;
  #pragma unroll
  for (int i = 0; i < AR; ++i)
    ar[i] = *(const uint4*)(A + (size_t)(m0 + r4 + i*64)*256 + s4*8);
  br = *(const uint4*)(Bt + (size_t)(n0 + r4)*256 + s4*8);
  f4 acc[MT][2] = {};
  #pragma unroll
  for (int kk = 0; kk < 8; ++kk){
    #pragma unroll
    for (int i = 0; i < AR; ++i)
      *(uint4*)&As[(r4 + i*64)*40 + s4*8] = ar[i];
    *(uint4*)&Bs[r4*40 + s4*8] = br;
    __syncthreads();
    if (kk < 7){
      #pragma unroll
      for (int i = 0; i < AR; ++i)
        ar[i] = *(const uint4*)(A + (size_t)(m0 + r4 + i*64)*256 + (kk+1)*32 + s4*8);
      br = *(const uint4*)(Bt + (size_t)(n0 + r4)*256 + (kk+1)*32 + s4*8);
    }
    #pragma unroll
    for (int mi = 0; mi < MT; ++mi){
      h8 af = *(const h8*)&As[(wr*(MT*16) + mi*16 + l15)*40 + q*8];
      #pragma unroll
      for (int nj = 0; nj < 2; ++nj){
        h8 bf = *(const h8*)&Bs[(wc*32 + nj*16 + l15)*40 + q*8];
        acc[mi][nj] = __builtin_amdgcn_mfma_f32_16x16x32_f16(af, bf, acc[mi][nj], 0,0,0);
      }
    }
    __syncthreads();
  }
  #pragma unroll
  for (int mi = 0; mi < MT; ++mi)
  #pragma unroll
  for (int nj = 0; nj < 2; ++nj){
    const int og = n0 + wc*32 + nj*16 + l15;
    const float bs = bias[og];
    #pragma unroll
    for (int r = 0; r < 4; ++r){
      const int mg = m0 + wr*(MT*16) + mi*16 + q*4 + r;
      const float v = acc[mi][nj][r] + bs;
      if (EPI == 0){
        const int h = og >> 6, j = og & 63;
        const int b = mg >> 10, n = mg & 1023;
        const size_t bhn = (size_t)(b*8+h)*1024 + n;
        if (j < 16)      Qh[bhn*16 + j]      = (_Float16)(v * QSCALE);
        else if (j < 32) Kh[bhn*16 + (j-16)] = (_Float16)v;
        else             Vh[bhn*32 + (j-32)] = (_Float16)v;
      } else {
        Out[(size_t)mg*256 + og] = v;
      }
    }
  }
}

// ---------------- pass1: rowsum of exp2 over m; Vs[d][n]=V[n][d]/sum -------
// Wave owns 32 n (2 tiles); K streamed through LDS in 64-row tiles.
__global__ __launch_bounds__(256) void pass1_k(
    const _Float16* __restrict__ Qh, const _Float16* __restrict__ Kh,
    const _Float16* __restrict__ Vh, _Float16* __restrict__ Vs)
{
  __shared__ __align__(16) _Float16 Ks[64*24];   // row stride 24 halves (48 B)
  const int t = threadIdx.x, lane = t & 63, wv = t >> 6;
  const int l15 = lane & 15, q = lane >> 4;
  const int bh = blockIdx.y;
  const int n0 = (blockIdx.x*4 + wv) * 32;
  const size_t qb = (size_t)bh*1024;
  const h4 af0 = *(const h4*)(Qh + (qb + n0 + l15)*16 + q*4);
  const h4 af1 = *(const h4*)(Qh + (qb + n0 + 16 + l15)*16 + q*4);
  f4 sm0 = {0.f,0.f,0.f,0.f}, sm1 = {0.f,0.f,0.f,0.f};
  const _Float16* kp = Kh + qb*16;
  const int sr = t >> 1, ss = t & 1;
  uint4 kr;
  if (t < 128) kr = *(const uint4*)(kp + sr*16 + ss*8);
  for (int mt = 0; mt < 1024; mt += 64){
    if (t < 128) *(uint4*)&Ks[sr*24 + ss*8] = kr;
    __syncthreads();
    if (t < 128 && mt + 64 < 1024)
      kr = *(const uint4*)(kp + (mt + 64 + sr)*16 + ss*8);
    #pragma unroll
    for (int sub = 0; sub < 4; ++sub){
      h4 bf = *(const h4*)&Ks[(sub*16 + l15)*24 + q*4];
      f4 z = {0.f,0.f,0.f,0.f};
      f4 d0 = __builtin_amdgcn_mfma_f32_16x16x16f16(af0, bf, z, 0,0,0);
      f4 d1 = __builtin_amdgcn_mfma_f32_16x16x16f16(af1, bf, z, 0,0,0);
      #pragma unroll
      for (int r = 0; r < 4; ++r){ sm0[r] += ex2(d0[r]); sm1[r] += ex2(d1[r]); }
    }
    __syncthreads();
  }
  #pragma unroll
  for (int st = 1; st < 16; st <<= 1){
    #pragma unroll
    for (int r = 0; r < 4; ++r){
      sm0[r] += __shfl_xor(sm0[r], st, 64);
      sm1[r] += __shfl_xor(sm1[r], st, 64);
    }
  }
  f4 cv0, cv1;
  #pragma unroll
  for (int r = 0; r < 4; ++r){ cv0[r] = 1.0f/sm0[r]; cv1[r] = 1.0f/sm1[r]; }
  #pragma unroll
  for (int half = 0; half < 2; ++half){
    const int dd = l15 + half*16;
    h4 o0, o1;
    #pragma unroll
    for (int r = 0; r < 4; ++r){
      o0[r] = (_Float16)((float)Vh[(qb + n0 + q*4 + r)*32 + dd] * cv0[r]);
      o1[r] = (_Float16)((float)Vh[(qb + n0 + 16 + q*4 + r)*32 + dd] * cv1[r]);
    }
    *(h4*)(Vs + ((size_t)bh*32 + dd)*1024 + n0 + q*4)      = o0;
    *(h4*)(Vs + ((size_t)bh*32 + dd)*1024 + n0 + 16 + q*4) = o1;
  }
}

// ---------------- pass2: out[m][d] = sum_n exp2(s[n][m]) * Vs[d][n] --------
// Wave owns 32 m (2 tiles); Q rows + Vs columns streamed through LDS in
// 64-n tiles. S-tile C/D layout IS the P^T A-frag layout (no shuffle).
// Epilogue: LDS-transpose 32x32 (m,d) tile, store X1h flat (b,d,h,m)
// == the reference transpose+reshape as an identity on flat indices.
__global__ __launch_bounds__(256) void pass2_k(
    const _Float16* __restrict__ Qh, const _Float16* __restrict__ Kh,
    const _Float16* __restrict__ Vs, _Float16* __restrict__ X1h)
{
  __shared__ __align__(16) _Float16 Qs[64*24];    // [n][k], stride 24
  __shared__ __align__(16) _Float16 Vss[32*72];   // [d][n-tile], stride 72
  __shared__ float Tt[4][32*33];
  const int t = threadIdx.x, lane = t & 63, wv = t >> 6;
  const int l15 = lane & 15, q = lane >> 4;
  const int bh = blockIdx.y;
  const int b  = bh >> 3, h = bh & 7;
  const int mb = (blockIdx.x*4 + wv) * 32;
  const size_t qb = (size_t)bh*1024;
  const h4 kf0 = *(const h4*)(Kh + (qb + mb + l15)*16 + q*4);
  const h4 kf1 = *(const h4*)(Kh + (qb + mb + 16 + l15)*16 + q*4);
  const _Float16* qp = Qh + qb*16;
  const _Float16* vp = Vs + (size_t)bh*32*1024;
  const int sr = t >> 1, ss = t & 1;        // Q staging: 64 rows x 2 segs
  const int vd = t >> 3, vc = (t & 7)*8;    // Vs staging: 32 d x 8 segs
  uint4 qr, vr;
  if (t < 128) qr = *(const uint4*)(qp + sr*16 + ss*8);
  vr = *(const uint4*)(vp + (size_t)vd*1024 + vc);
  f4 a00={0.f,0.f,0.f,0.f}, a01={0.f,0.f,0.f,0.f};
  f4 a10={0.f,0.f,0.f,0.f}, a11={0.f,0.f,0.f,0.f};
  for (int nt = 0; nt < 1024; nt += 64){
    if (t < 128) *(uint4*)&Qs[sr*24 + ss*8] = qr;
    *(uint4*)&Vss[vd*72 + vc] = vr;
    __syncthreads();
    if (nt + 64 < 1024){
      if (t < 128) qr = *(const uint4*)(qp + (nt + 64 + sr)*16 + ss*8);
      vr = *(const uint4*)(vp + (size_t)vd*1024 + nt + 64 + vc);
    }
    #pragma unroll
    for (int sub = 0; sub < 4; ++sub){
      h4 qf = *(const h4*)&Qs[(sub*16 + l15)*24 + q*4];
      h4 b0 = *(const h4*)&Vss[l15*72      + sub*16 + q*4];
      h4 b1 = *(const h4*)&Vss[(16+l15)*72 + sub*16 + q*4];
      f4 z = {0.f,0.f,0.f,0.f};
      f4 s0 = __builtin_amdgcn_mfma_f32_16x16x16f16(qf, kf0, z, 0,0,0);
      f4 s1 = __builtin_amdgcn_mfma_f32_16x16x16f16(qf, kf1, z, 0,0,0);
      h4 p0, p1;
      #pragma unroll
      for (int r = 0; r < 4; ++r){ p0[r] = (_Float16)ex2(s0[r]); p1[r] = (_Float16)ex2(s1[r]); }
      a00 = __builtin_amdgcn_mfma_f32_16x16x16f16(p0, b0, a00, 0,0,0);
      a01 = __builtin_amdgcn_mfma_f32_16x16x16f16(p0, b1, a01, 0,0,0);
      a10 = __builtin_amdgcn_mfma_f32_16x16x16f16(p1, b0, a10, 0,0,0);
      a11 = __builtin_amdgcn_mfma_f32_16x16x16f16(p1, b1, a11, 0,0,0);
    }
    __syncthreads();
  }
  // a00[r]=out[m=mb+4q+r][d=l15], a01->d=16+l15, a1x->m=mb+16+...; transpose.
  #pragma unroll
  for (int r = 0; r < 4; ++r){
    Tt[wv][(q*4 + r)*33      + l15]      = a00[r];
    Tt[wv][(q*4 + r)*33      + 16 + l15] = a01[r];
    Tt[wv][(16 + q*4 + r)*33 + l15]      = a10[r];
    Tt[wv][(16 + q*4 + r)*33 + 16 + l15] = a11[r];
  }
  __syncthreads();
  _Float16* xb = X1h + (size_t)b*262144 + (size_t)h*1024 + mb;
  const int mloc = lane & 31, dh = lane >> 5;
  #pragma unroll
  for (int r = 0; r < 16; ++r){
    const int d = r*2 + dh;
    xb[(size_t)d*8192 + mloc] = (_Float16)Tt[wv][mloc*33 + d];
  }
}

// ---------------- pe depthwise 3x3 + add + cast: 8 channels/thread --------
__global__ __launch_bounds__(256) void pe_add_k(
    const _Float16* __restrict__ Vh, const _Float16* __restrict__ X1h,
    const float* __restrict__ peW, const float* __restrict__ peB,
    _Float16* __restrict__ X2h)
{
  const int u = blockIdx.x*256 + threadIdx.x;   // 262144 threads, 8 c each
  const int c0 = (u & 31) * 8;
  const int tok = u >> 5;
  const int b = tok >> 10, n = tok & 1023;
  const int hs = n >> 5, ws = n & 31;
  const int h = c0 >> 5, d0 = c0 & 31;
  const size_t idx8 = (size_t)tok*256 + c0;
  float acc[8];
  {
    f4 b0v = *(const f4*)(peB + c0), b1v = *(const f4*)(peB + c0 + 4);
    #pragma unroll
    for (int j = 0; j < 4; ++j){ acc[j] = b0v[j]; acc[4+j] = b1v[j]; }
  }
  const _Float16* vb = Vh + (size_t)(b*8 + h)*32768 + d0;
  #pragma unroll
  for (int dy = 0; dy < 3; ++dy){
    const int y = hs + dy - 1;
    if ((unsigned)y < 32u){
      #pragma unroll
      for (int dx = 0; dx < 3; ++dx){
        const int x = ws + dx - 1;
        if ((unsigned)x < 32u){
          const int kk = dy*3 + dx;
          h8 vv = *(const h8*)(vb + (size_t)(y*32 + x)*32);
          f4 w0 = *(const f4*)(peW + kk*256 + c0);
          f4 w1 = *(const f4*)(peW + kk*256 + c0 + 4);
          #pragma unroll
          for (int j = 0; j < 4; ++j){
            acc[j]   += w0[j] * (float)vv[j];
            acc[4+j] += w1[j] * (float)vv[4+j];
          }
        }
      }
    }
  }
  h8 x1 = *(const h8*)(X1h + idx8);   // X1h flat (b,d,h,m) == output view order
  h8 o;
  #pragma unroll
  for (int j = 0; j < 8; ++j) o[j] = (_Float16)((float)x1[j] + acc[j]);
  *(h8*)(X2h + idx8) = o;
}

// --------------------------------------------------------------------------
extern "C" void kernel_launch(void* const* d_in, const int* in_sizes, int n_in,
                              void* d_out, int out_size, void* d_ws, size_t ws_size,
                              hipStream_t stream)
{
  const float* X    = (const float*)d_in[0];
  const float* qkvw = (const float*)d_in[1];
  const float* qg   = (const float*)d_in[2];
  const float* qb   = (const float*)d_in[3];
  const float* qm   = (const float*)d_in[4];
  const float* qv   = (const float*)d_in[5];
  const float* pew  = (const float*)d_in[6];
  const float* pg   = (const float*)d_in[7];
  const float* pb   = (const float*)d_in[8];
  const float* pm   = (const float*)d_in[9];
  const float* pv   = (const float*)d_in[10];
  const float* prw  = (const float*)d_in[11];
  const float* prg  = (const float*)d_in[12];
  const float* prb  = (const float*)d_in[13];
  const float* prm  = (const float*)d_in[14];
  const float* prv  = (const float*)d_in[15];

  char* ws = (char*)d_ws;
  // Xh and X2h share [0,4MB): Xh dead after qkv gemm, X2h born in pe_add.
  _Float16* Xh    = (_Float16*)(ws + 0);          //  4 MB
  _Float16* X2h   = (_Float16*)(ws + 0);          //  4 MB (overlay)
  _Float16* Qh    = (_Float16*)(ws + 4194304);    //  2 MB (pre-scaled)
  _Float16* Kh    = (_Float16*)(ws + 6291456);    //  2 MB
  _Float16* Vh    = (_Float16*)(ws + 8388608);    //  4 MB  (bh,n,d)
  _Float16* Vs    = (_Float16*)(ws + 12582912);   //  4 MB  (bh,d,n), /rowsum
  _Float16* X1h   = (_Float16*)(ws + 16777216);   //  4 MB  (b,d,h,m)
  _Float16* Wqkv  = (_Float16*)(ws + 20971520);   //  256 KB [o][c]
  float*    bqkv  = (float*)   (ws + 21233664);   //  2 KB
  _Float16* Wproj = (_Float16*)(ws + 21235712);   //  128 KB [o][c]
  float*    bproj = (float*)   (ws + 21366784);   //  1 KB
  float*    peW   = (float*)   (ws + 21367808);   //  9 KB
  float*    peB   = (float*)   (ws + 21377024);   //  1 KB

  prep_k<<<512, 256, 0, stream>>>(X, qkvw, qg, qb, qm, qv, pew, pg, pb, pm, pv,
                                  prw, prg, prb, prm, prv,
                                  Xh, Wqkv, bqkv, Wproj, bproj, peW, peB);
  gemm_staged_k<0,4><<<dim3(64, 8), 256, 0, stream>>>(Xh, Wqkv, bqkv,
                                                      Qh, Kh, Vh, nullptr);
  pass1_k<<<dim3(8, 64), 256, 0, stream>>>(Qh, Kh, Vh, Vs);
  pass2_k<<<dim3(8, 64), 256, 0, stream>>>(Qh, Kh, Vs, X1h);
  pe_add_k<<<1024, 256, 0, stream>>>(Vh, X1h, peW, peB, X2h);
  gemm_staged_k<1,2><<<dim3(128, 4), 256, 0, stream>>>(X2h, Wproj, bproj,
                                                       nullptr, nullptr, nullptr,
                                                       (float*)d_out);
}